// Round 4
// baseline (3842.511 us; speedup 1.0000x reference)
//
#include <hip/hip_runtime.h>
#include <hip/hip_bf16.h>
#include <cstdint>
#include <cstddef>

// ---------------------------------------------------------------------------
// ImprovedCrossScaleGNN on MI355X (gfx950).
// Dtypes (R3 post-mortem): inputs float32 + int32, OUTPUT FLOAT32.
// R2/R3 bit-identical error came from writing bf16 into an f32 d_out
// (unwritten tail dominated the absmax). Internal compute: bf16 MFMA for
// GEMMs, f32 for BN/LN/softmax/aggregation. Peak ws ~52 MB.
// ---------------------------------------------------------------------------

typedef __attribute__((ext_vector_type(8))) short bf16x8;
typedef __attribute__((ext_vector_type(4))) float f32x4;

#define EPSV 1e-5f

__device__ __forceinline__ float b2f(unsigned short u) {
    union { unsigned int i; float f; } x; x.i = ((unsigned int)u) << 16; return x.f;
}
__device__ __forceinline__ unsigned short f2b(float f) {
    union { float f; unsigned int i; } x; x.f = f;
    unsigned int i = x.i;
    return (unsigned short)((i + 0x7fffu + ((i >> 16) & 1u)) >> 16);
}

// ---------------- degree / dinv ----------------
__global__ void degree_kernel(const int* __restrict__ dst, float* __restrict__ deg, int nE) {
    int t = blockIdx.x * blockDim.x + threadIdx.x;
    if (t >= nE) return;
    atomicAdd(&deg[dst[t]], 1.0f);
}

__global__ void dinv_kernel(float* __restrict__ deg, int n) {
    int t = blockIdx.x * blockDim.x + threadIdx.x;
    if (t >= n) return;
    deg[t] = rsqrtf(deg[t] + 1.0f);  // +1 self-loop
}

// ---------------- f32 -> bf16 cast ----------------
__global__ void cast_kernel(const float* __restrict__ in, unsigned short* __restrict__ out,
                            int n) {
    int idx = blockIdx.x * blockDim.x + threadIdx.x;
    if (idx >= n) return;
    out[idx] = f2b(in[idx]);
}

// ---------------- f32 transpose+cast: in K x C -> out bf16 C x K -------------
__global__ void transpose_kernel(const float* __restrict__ in,
                                 unsigned short* __restrict__ out, int K, int C) {
    int idx = blockIdx.x * blockDim.x + threadIdx.x;
    if (idx >= K * C) return;
    int k = idx / C, c = idx - k * C;
    out[c * K + k] = f2b(in[idx]);
}

// ---------------- MFMA GEMM: D[M x Ncol] = A[M x 128] @ Bt[Ncol x 128]^T (+bias) ----
// A frag A[m=lane&15][k=(lane>>4)*8+j]; B frag B[k=(lane>>4)*8+j][n=lane&15];
// D: col=lane&15, row=(lane>>4)*4+reg.  (m89/m91/m120-verified layouts)
template <bool OUT_BF16>
__global__ void gemm_kernel(const unsigned short* __restrict__ A,
                            const unsigned short* __restrict__ Bt,
                            const float* __restrict__ bias,
                            void* __restrict__ D, int M, int Ncol) {
    int wave = (blockIdx.x * blockDim.x + threadIdx.x) >> 6;
    int lane = threadIdx.x & 63;
    int m0 = wave * 16;
    if (m0 >= M) return;
    int r = lane & 15, q = lane >> 4;
    int arow = m0 + r; if (arow >= M) arow = M - 1;
    const unsigned short* ap = A + (size_t)arow * 128 + q * 8;
    bf16x8 afrag[4];
#pragma unroll
    for (int kc = 0; kc < 4; ++kc)
        afrag[kc] = *(const bf16x8*)(const void*)(ap + kc * 32);

    for (int n0 = 0; n0 < Ncol; n0 += 16) {
        int bcol = n0 + r;
        const unsigned short* bp = Bt + (size_t)bcol * 128 + q * 8;
        f32x4 acc = {0.f, 0.f, 0.f, 0.f};
#pragma unroll
        for (int kc = 0; kc < 4; ++kc) {
            bf16x8 bfrag = *(const bf16x8*)(const void*)(bp + kc * 32);
            acc = __builtin_amdgcn_mfma_f32_16x16x32_bf16(afrag[kc], bfrag, acc, 0, 0, 0);
        }
        float bv = bias ? bias[bcol] : 0.f;
#pragma unroll
        for (int t = 0; t < 4; ++t) {
            int row = m0 + q * 4 + t;
            if (row < M) {
                float v = acc[t] + bv;
                if (OUT_BF16) ((unsigned short*)D)[(size_t)row * Ncol + bcol] = f2b(v);
                else          ((float*)D)[(size_t)row * Ncol + bcol] = v;
            }
        }
    }
}

// ---------------- GCN aggregation ----------------
// agg[i][f] = m[i][f]*dinv[i]^2 + b[f]   (self-loop + bias); m is bf16
__global__ void agg_init_kernel(const unsigned short* __restrict__ m,
                                const float* __restrict__ dinv,
                                const float* __restrict__ b, float* __restrict__ agg,
                                int n) {
    int idx = blockIdx.x * blockDim.x + threadIdx.x;
    if (idx >= n * 128) return;
    int node = idx >> 7, f = idx & 127;
    float di = dinv[node];
    agg[idx] = b2f(m[idx]) * di * di + b[f];
}

// 32 lanes per edge, 4 feats each (ushort4 bf16 gather + 4 f32 atomics)
__global__ void scatter_kernel(const unsigned short* __restrict__ m, const int* __restrict__ src,
                               const int* __restrict__ dst, const float* __restrict__ dinv,
                               float* __restrict__ agg, int nE) {
    int t = blockIdx.x * blockDim.x + threadIdx.x;
    int e = t >> 5;
    if (e >= nE) return;
    int sub = t & 31;
    int s = src[e], d = dst[e];
    float w = dinv[s] * dinv[d];
    ushort4 v = *((const ushort4*)(m + (size_t)s * 128) + sub);
    float* ap = agg + (size_t)d * 128 + sub * 4;
    atomicAdd(ap + 0, b2f(v.x) * w);
    atomicAdd(ap + 1, b2f(v.y) * w);
    atomicAdd(ap + 2, b2f(v.z) * w);
    atomicAdd(ap + 3, b2f(v.w) * w);
}

// ---------------- BatchNorm (over rows), biased var ----------------
__global__ void bn_stats_kernel(const float* __restrict__ x, float* __restrict__ sums,
                                int Nrows, int F, int rpb) {
    int f = threadIdx.x;
    int r0 = blockIdx.x * rpb;
    int r1 = r0 + rpb; if (r1 > Nrows) r1 = Nrows;
    float s = 0.f, s2 = 0.f;
    for (int r = r0; r < r1; ++r) {
        float v = x[(size_t)r * F + f];
        s += v; s2 += v * v;
    }
    atomicAdd(&sums[f], s);
    atomicAdd(&sums[F + f], s2);
}

__global__ void bn_finalize_kernel(const float* __restrict__ sums,
                                   const float* __restrict__ g,
                                   const float* __restrict__ beta,
                                   float* __restrict__ params, int Nrows, int F) {
    int f = threadIdx.x;
    if (f >= F) return;
    float inv = 1.f / (float)Nrows;
    float mean = sums[f] * inv;
    float var = sums[F + f] * inv - mean * mean;
    float rstd = rsqrtf(var + EPSV);
    float sc = g[f] * rstd;
    params[f] = sc;
    params[F + f] = beta[f] - mean * sc;
}

// h_new = relu(agg*scale+shift) (+ h_prev from hb); writes bf16 hb
__global__ void bn_apply_kernel(const float* __restrict__ agg, const float* __restrict__ params,
                                unsigned short* __restrict__ hb, int total, int useRes) {
    int idx = blockIdx.x * blockDim.x + threadIdx.x;
    if (idx >= total) return;
    int f = idx & 127;
    float v = agg[idx] * params[f] + params[128 + f];
    v = fmaxf(v, 0.f);
    if (useRes) v += b2f(hb[idx]);
    hb[idx] = f2b(v);
}

// ---------------- fused MHA + mean + residual + LayerNorm ----------------
// 1 wave per 16 rows (8 nodes). Rows interleave (node, comm[map[node]]).
__global__ __launch_bounds__(64) void mha_fused_kernel(
    const unsigned short* __restrict__ hbn, const unsigned short* __restrict__ hbc,
    const int* __restrict__ map,
    const unsigned short* __restrict__ WinB,   // [384][128] bf16 (= attn_in_w)
    const float* __restrict__ bin,             // [384]
    const unsigned short* __restrict__ WoutB,  // [128][128] bf16 (= attn_out_w)
    const float* __restrict__ bout,            // [128]
    const float* __restrict__ lng, const float* __restrict__ lnb,
    unsigned short* __restrict__ hfin, int nN, int nC) {
    __shared__ unsigned short qkv_s[16 * 384];
    __shared__ unsigned short obf_s[16 * 128];
    __shared__ float att_s[8 * 128];

    int b = blockIdx.x;
    int lane = threadIdx.x;
    int r = lane & 15, q = lane >> 4;

    // ---- phase A: in-proj GEMM (16 x 384) ----
    int anode = b * 8 + (r >> 1);
    if (anode >= nN) anode = nN - 1;
    const unsigned short* arow;
    if (r & 1) {
        int c = map[anode]; c = c < 0 ? 0 : (c >= nC ? nC - 1 : c);
        arow = hbc + (size_t)c * 128;
    } else {
        arow = hbn + (size_t)anode * 128;
    }
    bf16x8 afrag[4];
#pragma unroll
    for (int kc = 0; kc < 4; ++kc)
        afrag[kc] = *(const bf16x8*)(const void*)(arow + q * 8 + kc * 32);

    for (int n0 = 0; n0 < 384; n0 += 16) {
        const unsigned short* bp = WinB + (size_t)(n0 + r) * 128 + q * 8;
        f32x4 acc = {0.f, 0.f, 0.f, 0.f};
#pragma unroll
        for (int kc = 0; kc < 4; ++kc) {
            bf16x8 bfrag = *(const bf16x8*)(const void*)(bp + kc * 32);
            acc = __builtin_amdgcn_mfma_f32_16x16x32_bf16(afrag[kc], bfrag, acc, 0, 0, 0);
        }
        float bv = bin[n0 + r];
#pragma unroll
        for (int t = 0; t < 4; ++t)
            qkv_s[(q * 4 + t) * 384 + n0 + r] = f2b(acc[t] + bv);
    }
    __syncthreads();

    // ---- phase B: attention, lane = (node_local = lane>>3, head = lane&7) ----
    {
        int nl = lane >> 3, h = lane & 7;
        const unsigned short* r0 = qkv_s + (2 * nl) * 384;
        const unsigned short* r1 = r0 + 384;
        int ho = h * 16;
        float s00 = 0, s01 = 0, s10 = 0, s11 = 0;
#pragma unroll
        for (int d = 0; d < 16; ++d) {
            float q0 = b2f(r0[ho + d]),       q1 = b2f(r1[ho + d]);
            float k0 = b2f(r0[128 + ho + d]), k1 = b2f(r1[128 + ho + d]);
            s00 += q0 * k0; s01 += q0 * k1;
            s10 += q1 * k0; s11 += q1 * k1;
        }
        s00 *= 0.25f; s01 *= 0.25f; s10 *= 0.25f; s11 *= 0.25f;
        float m0 = fmaxf(s00, s01), m1 = fmaxf(s10, s11);
        float e00 = __expf(s00 - m0), e01 = __expf(s01 - m0);
        float e10 = __expf(s10 - m1), e11 = __expf(s11 - m1);
        float i0 = 1.f / (e00 + e01), i1 = 1.f / (e10 + e11);
        float a00 = e00 * i0, a01 = e01 * i0;
        float a10 = e10 * i1, a11 = e11 * i1;
        unsigned short* o0 = obf_s + (2 * nl) * 128 + ho;
        unsigned short* o1 = o0 + 128;
#pragma unroll
        for (int d = 0; d < 16; ++d) {
            float v0 = b2f(r0[256 + ho + d]), v1 = b2f(r1[256 + ho + d]);
            o0[d] = f2b(a00 * v0 + a01 * v1);
            o1[d] = f2b(a10 * v0 + a11 * v1);
        }
    }
    __syncthreads();

    // ---- phase C: out-proj GEMM (16 x 128) + bias + mean over S ----
    bf16x8 ofrag[4];
#pragma unroll
    for (int kc = 0; kc < 4; ++kc)
        ofrag[kc] = *(const bf16x8*)(const void*)(obf_s + r * 128 + q * 8 + kc * 32);

    for (int n0 = 0; n0 < 128; n0 += 16) {
        const unsigned short* bp = WoutB + (size_t)(n0 + r) * 128 + q * 8;
        f32x4 acc = {0.f, 0.f, 0.f, 0.f};
#pragma unroll
        for (int kc = 0; kc < 4; ++kc) {
            bf16x8 bfrag = *(const bf16x8*)(const void*)(bp + kc * 32);
            acc = __builtin_amdgcn_mfma_f32_16x16x32_bf16(ofrag[kc], bfrag, acc, 0, 0, 0);
        }
        float bv = bout[n0 + r];
        // rows q*4+t: (t=0,1) -> local node q*2 (seq 0/1), (t=2,3) -> q*2+1
        att_s[(q * 2 + 0) * 128 + n0 + r] = 0.5f * (acc[0] + acc[1]) + bv;
        att_s[(q * 2 + 1) * 128 + n0 + r] = 0.5f * (acc[2] + acc[3]) + bv;
    }
    __syncthreads();

    // ---- phase D: residual + LayerNorm (8 lanes per node, 16 cols each) ----
    {
        int nl = lane >> 3, j = lane & 7;
        int gnode = b * 8 + nl; if (gnode >= nN) gnode = nN - 1;
        const unsigned short* hrow = hbn + (size_t)gnode * 128 + j * 16;
        float x[16]; float s = 0.f, s2 = 0.f;
#pragma unroll
        for (int i = 0; i < 16; ++i) {
            x[i] = att_s[nl * 128 + j * 16 + i] + b2f(hrow[i]);
            s += x[i]; s2 += x[i] * x[i];
        }
        s += __shfl_xor(s, 1);  s2 += __shfl_xor(s2, 1);
        s += __shfl_xor(s, 2);  s2 += __shfl_xor(s2, 2);
        s += __shfl_xor(s, 4);  s2 += __shfl_xor(s2, 4);
        float mu = s * (1.f / 128.f);
        float var = s2 * (1.f / 128.f) - mu * mu;
        float rstd = rsqrtf(var + EPSV);
        unsigned short* orow = hfin + (size_t)gnode * 128 + j * 16;
#pragma unroll
        for (int i = 0; i < 16; ++i)
            orow[i] = f2b((x[i] - mu) * rstd * lng[j * 16 + i] + lnb[j * 16 + i]);
    }
}

// ---------------- classifier tail: BN+ReLU + Linear(64,10) + log_softmax ------
// OUTPUT IS FLOAT32.
__global__ void final_kernel(const float* __restrict__ z, const float* __restrict__ bnp,
                             const float* __restrict__ W2,
                             const float* __restrict__ b2v,
                             float* __restrict__ out, int nN) {
    int node = blockIdx.x;
    int lane = threadIdx.x;  // 64
    float v = z[(size_t)node * 64 + lane] * bnp[lane] + bnp[64 + lane];
    v = fmaxf(v, 0.f);
    float p[10];
    const float* wrow = W2 + lane * 10;
#pragma unroll
    for (int c = 0; c < 10; ++c) p[c] = v * wrow[c];
#pragma unroll
    for (int off = 32; off >= 1; off >>= 1) {
#pragma unroll
        for (int c = 0; c < 10; ++c) p[c] += __shfl_xor(p[c], off);
    }
    float l[10], mx = -1e30f;
#pragma unroll
    for (int c = 0; c < 10; ++c) { l[c] = p[c] + b2v[c]; mx = fmaxf(mx, l[c]); }
    float se = 0.f;
#pragma unroll
    for (int c = 0; c < 10; ++c) se += expf(l[c] - mx);
    float lse = mx + logf(se);
    if (lane < 10) out[(size_t)node * 10 + lane] = l[lane] - lse;
}

// ---------------------------------------------------------------------------
static inline int cdiv(long a, long b) { return (int)((a + b - 1) / b); }

extern "C" void kernel_launch(void* const* d_in, const int* in_sizes, int n_in,
                              void* d_out, int out_size, void* d_ws, size_t ws_size,
                              hipStream_t stream) {
    const float* node_feat = (const float*)d_in[0];
    const int*   nedge     = (const int*)d_in[1];
    const float* comm_feat = (const float*)d_in[2];
    const int*   cedge     = (const int*)d_in[3];
    const int*   n2c       = (const int*)d_in[4];
    const float* node_W    = (const float*)d_in[5];
    const float* node_b    = (const float*)d_in[6];
    const float* node_g    = (const float*)d_in[7];
    const float* node_beta = (const float*)d_in[8];
    const float* comm_W    = (const float*)d_in[9];
    const float* comm_b    = (const float*)d_in[10];
    const float* comm_g    = (const float*)d_in[11];
    const float* comm_beta = (const float*)d_in[12];
    const float* attn_in_w = (const float*)d_in[13];
    const float* attn_in_b = (const float*)d_in[14];
    const float* attn_out_w= (const float*)d_in[15];
    const float* attn_out_b= (const float*)d_in[16];
    const float* ln_g      = (const float*)d_in[17];
    const float* ln_b      = (const float*)d_in[18];
    const float* cls_W1    = (const float*)d_in[19];
    const float* cls_b1    = (const float*)d_in[20];
    const float* cls_bn_g  = (const float*)d_in[21];
    const float* cls_bn_b  = (const float*)d_in[22];
    const float* cls_W2    = (const float*)d_in[23];
    const float* cls_b2    = (const float*)d_in[24];

    const int nN = in_sizes[0] / 128;
    const int nE = in_sizes[1] / 2;
    const int nC = in_sizes[2] / 128;
    const int cE = in_sizes[3] / 2;

    // ---- workspace layout, peak ~52 MB ----
    char* ws = (char*)d_ws;
    size_t off = 0;
    auto alloc = [&](size_t bytes) -> char* {
        char* p = ws + off;
        off = (off + bytes + 255) & ~(size_t)255;
        return p;
    };
    float*          deg_n = (float*)alloc((size_t)nN * 4);
    float*          deg_c = (float*)alloc((size_t)nC * 4);
    unsigned short* hb_n  = (unsigned short*)alloc((size_t)nN * 256);  // bf16 h (node)
    unsigned short* hb_c  = (unsigned short*)alloc((size_t)nC * 256);
    unsigned short* cfb   = (unsigned short*)alloc((size_t)nC * 256);  // comm feat bf16
    unsigned short* m_cb  = (unsigned short*)alloc((size_t)nC * 256);
    float*          agg_c = (float*)alloc((size_t)nC * 512);
    float*          bn_sums   = (float*)alloc(1024);
    float*          bn_params = (float*)alloc(1024);
    unsigned short* WtN  = (unsigned short*)alloc((size_t)3 * 16384 * 2);
    unsigned short* WtC  = (unsigned short*)alloc((size_t)3 * 16384 * 2);
    unsigned short* W1t  = (unsigned short*)alloc((size_t)64 * 128 * 2);
    unsigned short* WinB = (unsigned short*)alloc((size_t)384 * 128 * 2);
    unsigned short* WoutB= (unsigned short*)alloc((size_t)128 * 128 * 2);
    unsigned short* m_nb = (unsigned short*)alloc((size_t)nN * 256);   // bf16 messages
    float*          agg_n= (float*)alloc((size_t)nN * 512);            // f32 (atomics)
    // aliases (disjoint liveness):
    unsigned short* nfb  = (unsigned short*)agg_n;  // node feat bf16; dead before agg_init L0
    unsigned short* hfin = m_nb;                    // written after node GCN done
    float*          z    = agg_n;                   // written after node GCN done

    // ---- degrees / dinv ----
    hipMemsetAsync(deg_n, 0, (size_t)nN * 4, stream);
    hipMemsetAsync(deg_c, 0, (size_t)nC * 4, stream);
    degree_kernel<<<cdiv(nE, 256), 256, 0, stream>>>(nedge + nE, deg_n, nE);
    degree_kernel<<<cdiv(cE, 256), 256, 0, stream>>>(cedge + cE, deg_c, cE);
    dinv_kernel<<<cdiv(nN, 256), 256, 0, stream>>>(deg_n, nN);
    dinv_kernel<<<cdiv(nC, 256), 256, 0, stream>>>(deg_c, nC);

    // ---- weight transposes/casts ----
    for (int i = 0; i < 3; ++i) {
        transpose_kernel<<<64, 256, 0, stream>>>(node_W + i * 16384, WtN + i * 16384, 128, 128);
        transpose_kernel<<<64, 256, 0, stream>>>(comm_W + i * 16384, WtC + i * 16384, 128, 128);
    }
    transpose_kernel<<<32, 256, 0, stream>>>(cls_W1, W1t, 128, 64);
    cast_kernel<<<192, 256, 0, stream>>>(attn_in_w, WinB, 49152);
    cast_kernel<<<64, 256, 0, stream>>>(attn_out_w, WoutB, 16384);
    cast_kernel<<<cdiv((long)nC * 128, 256), 256, 0, stream>>>(comm_feat, cfb, nC * 128);

    // ---- GCN stacks ----
    auto gcn_layer = [&](int layer, int n, int e, const int* src, const int* dst,
                         const unsigned short* A, const unsigned short* Wt,
                         const float* bvec, const float* g, const float* beta,
                         float* dinv, unsigned short* m, float* agg, unsigned short* hb) {
        int waves = (n + 15) / 16;
        gemm_kernel<true><<<cdiv((long)waves * 64, 256), 256, 0, stream>>>(
            A, Wt, (const float*)nullptr, m, n, 128);
        agg_init_kernel<<<cdiv((long)n * 128, 256), 256, 0, stream>>>(m, dinv, bvec, agg, n);
        scatter_kernel<<<cdiv((long)e * 32, 256), 256, 0, stream>>>(m, src, dst, dinv, agg, e);
        hipMemsetAsync(bn_sums, 0, 1024, stream);
        bn_stats_kernel<<<cdiv(n, 128), 128, 0, stream>>>(agg, bn_sums, n, 128, 128);
        bn_finalize_kernel<<<1, 128, 0, stream>>>(bn_sums, g, beta, bn_params, n, 128);
        bn_apply_kernel<<<cdiv((long)n * 128, 256), 256, 0, stream>>>(
            agg, bn_params, hb, n * 128, layer > 0 ? 1 : 0);
    };

    // node branch: layer-0 A = nfb (cast right before; nfb aliases agg_n, dead
    // before agg_init of layer 0 writes agg_n)
    cast_kernel<<<cdiv((long)nN * 128, 256), 256, 0, stream>>>(node_feat, nfb, nN * 128);
    for (int i = 0; i < 3; ++i)
        gcn_layer(i, nN, nE, nedge, nedge + nE, i == 0 ? nfb : hb_n, WtN + i * 16384,
                  node_b + i * 128, node_g + i * 128, node_beta + i * 128,
                  deg_n, m_nb, agg_n, hb_n);
    for (int i = 0; i < 3; ++i)
        gcn_layer(i, nC, cE, cedge, cedge + cE, i == 0 ? cfb : hb_c, WtC + i * 16384,
                  comm_b + i * 128, comm_g + i * 128, comm_beta + i * 128,
                  deg_c, m_cb, agg_c, hb_c);

    // ---- fused MHA + mean + residual + LN -> hfin (aliases m_nb) ----
    mha_fused_kernel<<<cdiv(nN, 8), 64, 0, stream>>>(
        hb_n, hb_c, n2c, WinB, attn_in_b, WoutB, attn_out_b, ln_g, ln_b, hfin, nN, nC);

    // ---- classifier ----
    int waves1 = (nN + 15) / 16;
    gemm_kernel<false><<<cdiv((long)waves1 * 64, 256), 256, 0, stream>>>(
        hfin, W1t, cls_b1, z, nN, 64);
    hipMemsetAsync(bn_sums, 0, 1024, stream);
    bn_stats_kernel<<<cdiv(nN, 128), 64, 0, stream>>>(z, bn_sums, nN, 64, 128);
    bn_finalize_kernel<<<1, 64, 0, stream>>>(bn_sums, cls_bn_g, cls_bn_b, bn_params, nN, 64);
    final_kernel<<<nN, 64, 0, stream>>>(z, bn_params, cls_W2, cls_b2,
                                        (float*)d_out, nN);
}

// Round 5
// 1027.909 us; speedup vs baseline: 3.7382x; 3.7382x over previous
//
#include <hip/hip_runtime.h>
#include <hip/hip_bf16.h>
#include <cstdint>
#include <cstddef>

// ---------------------------------------------------------------------------
// ImprovedCrossScaleGNN on MI355X (gfx950).
// Inputs float32 + int32, output float32. Internal: bf16 MFMA GEMMs, f32
// BN/LN/softmax/aggregation.
// R4->R5: scatter-atomic aggregation (1.2 GB HBM writes/layer, 78% of time)
// replaced by CSR build (once) + wave-per-node gather (writes agg once).
// ---------------------------------------------------------------------------

typedef __attribute__((ext_vector_type(8))) short bf16x8;
typedef __attribute__((ext_vector_type(4))) float f32x4;

#define EPSV 1e-5f

__device__ __forceinline__ float b2f(unsigned short u) {
    union { unsigned int i; float f; } x; x.i = ((unsigned int)u) << 16; return x.f;
}
__device__ __forceinline__ unsigned short f2b(float f) {
    union { float f; unsigned int i; } x; x.f = f;
    unsigned int i = x.i;
    return (unsigned short)((i + 0x7fffu + ((i >> 16) & 1u)) >> 16);
}

// ---------------- CSR build ----------------
__global__ void count_kernel(const int* __restrict__ dst, int* __restrict__ cnt, int nE) {
    int t = blockIdx.x * blockDim.x + threadIdx.x;
    if (t >= nE) return;
    atomicAdd(&cnt[dst[t]], 1);
}

__global__ void dinv_kernel(const int* __restrict__ cnt, float* __restrict__ dinv, int n) {
    int t = blockIdx.x * blockDim.x + threadIdx.x;
    if (t >= n) return;
    dinv[t] = rsqrtf((float)cnt[t] + 1.0f);  // +1 self-loop
}

// block-wise exclusive scan (1024/block), Hillis-Steele in LDS
__global__ void scan_block_kernel(const int* __restrict__ cnt, int* __restrict__ excl,
                                  int* __restrict__ bsum, int n) {
    __shared__ int tmp[2048];
    int tid = threadIdx.x;
    int gid = blockIdx.x * 1024 + tid;
    int v = (gid < n) ? cnt[gid] : 0;
    int buf = 0;
    tmp[tid] = v;
    __syncthreads();
    for (int d = 1; d < 1024; d <<= 1) {
        int t = tmp[buf * 1024 + tid];
        int add = (tid >= d) ? tmp[buf * 1024 + tid - d] : 0;
        tmp[(1 - buf) * 1024 + tid] = t + add;
        buf = 1 - buf;
        __syncthreads();
    }
    int inc = tmp[buf * 1024 + tid];
    if (gid < n) excl[gid] = inc - v;
    if (tid == 1023) bsum[blockIdx.x] = inc;
}

__global__ void scan_sums_kernel(int* __restrict__ bsum, int nb) {
    if (threadIdx.x == 0 && blockIdx.x == 0) {
        int acc = 0;
        for (int i = 0; i < nb; ++i) { int t = bsum[i]; bsum[i] = acc; acc += t; }
    }
}

// adds block offsets; also writes row_start[n] = nE
__global__ void scan_add_kernel(int* __restrict__ row_start, const int* __restrict__ bsum,
                                int n, int nE) {
    int gid = blockIdx.x * blockDim.x + threadIdx.x;
    if (gid < n) row_start[gid] += bsum[gid >> 10];
    else if (gid == n) row_start[n] = nE;
}

__global__ void fill_kernel(const int* __restrict__ src, const int* __restrict__ dst,
                            const float* __restrict__ dinv, const int* __restrict__ row_start,
                            int* __restrict__ cursor, int* __restrict__ csrc,
                            float* __restrict__ cw, int nE) {
    int e = blockIdx.x * blockDim.x + threadIdx.x;
    if (e >= nE) return;
    int s = src[e], d = dst[e];
    int pos = atomicAdd(&cursor[d], 1);
    int slot = row_start[d] + pos;
    csrc[slot] = s;
    cw[slot] = dinv[s] * dinv[d];
}

// ---------------- f32 -> bf16 cast ----------------
__global__ void cast_kernel(const float* __restrict__ in, unsigned short* __restrict__ out,
                            int n) {
    int idx = blockIdx.x * blockDim.x + threadIdx.x;
    if (idx >= n) return;
    out[idx] = f2b(in[idx]);
}

// ---------------- f32 transpose+cast: in K x C -> out bf16 C x K -------------
__global__ void transpose_kernel(const float* __restrict__ in,
                                 unsigned short* __restrict__ out, int K, int C) {
    int idx = blockIdx.x * blockDim.x + threadIdx.x;
    if (idx >= K * C) return;
    int k = idx / C, c = idx - k * C;
    out[c * K + k] = f2b(in[idx]);
}

// ---------------- MFMA GEMM: D[M x Ncol] = A[M x 128] @ Bt[Ncol x 128]^T (+bias) ----
// A frag A[m=lane&15][k=(lane>>4)*8+j]; B frag B[k=(lane>>4)*8+j][n=lane&15];
// D: col=lane&15, row=(lane>>4)*4+reg.
template <bool OUT_BF16>
__global__ void gemm_kernel(const unsigned short* __restrict__ A,
                            const unsigned short* __restrict__ Bt,
                            const float* __restrict__ bias,
                            void* __restrict__ D, int M, int Ncol) {
    int wave = (blockIdx.x * blockDim.x + threadIdx.x) >> 6;
    int lane = threadIdx.x & 63;
    int m0 = wave * 16;
    if (m0 >= M) return;
    int r = lane & 15, q = lane >> 4;
    int arow = m0 + r; if (arow >= M) arow = M - 1;
    const unsigned short* ap = A + (size_t)arow * 128 + q * 8;
    bf16x8 afrag[4];
#pragma unroll
    for (int kc = 0; kc < 4; ++kc)
        afrag[kc] = *(const bf16x8*)(const void*)(ap + kc * 32);

    for (int n0 = 0; n0 < Ncol; n0 += 16) {
        int bcol = n0 + r;
        const unsigned short* bp = Bt + (size_t)bcol * 128 + q * 8;
        f32x4 acc = {0.f, 0.f, 0.f, 0.f};
#pragma unroll
        for (int kc = 0; kc < 4; ++kc) {
            bf16x8 bfrag = *(const bf16x8*)(const void*)(bp + kc * 32);
            acc = __builtin_amdgcn_mfma_f32_16x16x32_bf16(afrag[kc], bfrag, acc, 0, 0, 0);
        }
        float bv = bias ? bias[bcol] : 0.f;
#pragma unroll
        for (int t = 0; t < 4; ++t) {
            int row = m0 + q * 4 + t;
            if (row < M) {
                float v = acc[t] + bv;
                if (OUT_BF16) ((unsigned short*)D)[(size_t)row * Ncol + bcol] = f2b(v);
                else          ((float*)D)[(size_t)row * Ncol + bcol] = v;
            }
        }
    }
}

// ---------------- GCN aggregation: wave per dst node, CSR gather -------------
// agg[d][f] = sum_in-edges m[s][f]*w + m[d][f]*dinv[d]^2 + bias[f]
__global__ __launch_bounds__(256) void gather_kernel(
    const unsigned short* __restrict__ m, const int* __restrict__ row_start,
    const int* __restrict__ csrc, const float* __restrict__ cw,
    const float* __restrict__ dinv, const float* __restrict__ bias,
    float* __restrict__ agg, int n) {
    int wave = (blockIdx.x * blockDim.x + threadIdx.x) >> 6;
    if (wave >= n) return;
    int lane = threadIdx.x & 63;
    int start = row_start[wave], end = row_start[wave + 1];
    float a0 = 0.f, a1 = 0.f;
    for (int i = start; i < end; ++i) {
        int s = csrc[i];
        float w = cw[i];
        unsigned int v = *(const unsigned int*)(m + (size_t)s * 128 + 2 * lane);
        a0 += b2f((unsigned short)(v & 0xffff)) * w;
        a1 += b2f((unsigned short)(v >> 16)) * w;
    }
    float di = dinv[wave];
    float wself = di * di;
    unsigned int v = *(const unsigned int*)(m + (size_t)wave * 128 + 2 * lane);
    a0 += b2f((unsigned short)(v & 0xffff)) * wself + bias[2 * lane];
    a1 += b2f((unsigned short)(v >> 16)) * wself + bias[2 * lane + 1];
    float2 o; o.x = a0; o.y = a1;
    ((float2*)(agg + (size_t)wave * 128))[lane] = o;
}

// ---------------- BatchNorm (over rows), biased var ----------------
__global__ void bn_stats_kernel(const float* __restrict__ x, float* __restrict__ sums,
                                int Nrows, int F, int rpb) {
    int f = threadIdx.x;
    int r0 = blockIdx.x * rpb;
    int r1 = r0 + rpb; if (r1 > Nrows) r1 = Nrows;
    float s = 0.f, s2 = 0.f;
    for (int r = r0; r < r1; ++r) {
        float v = x[(size_t)r * F + f];
        s += v; s2 += v * v;
    }
    atomicAdd(&sums[f], s);
    atomicAdd(&sums[F + f], s2);
}

__global__ void bn_finalize_kernel(const float* __restrict__ sums,
                                   const float* __restrict__ g,
                                   const float* __restrict__ beta,
                                   float* __restrict__ params, int Nrows, int F) {
    int f = threadIdx.x;
    if (f >= F) return;
    float inv = 1.f / (float)Nrows;
    float mean = sums[f] * inv;
    float var = sums[F + f] * inv - mean * mean;
    float rstd = rsqrtf(var + EPSV);
    float sc = g[f] * rstd;
    params[f] = sc;
    params[F + f] = beta[f] - mean * sc;
}

// h_new = relu(agg*scale+shift) (+ h_prev from hb); writes bf16 hb
__global__ void bn_apply_kernel(const float* __restrict__ agg, const float* __restrict__ params,
                                unsigned short* __restrict__ hb, int total, int useRes) {
    int idx = blockIdx.x * blockDim.x + threadIdx.x;
    if (idx >= total) return;
    int f = idx & 127;
    float v = agg[idx] * params[f] + params[128 + f];
    v = fmaxf(v, 0.f);
    if (useRes) v += b2f(hb[idx]);
    hb[idx] = f2b(v);
}

// ---------------- fused MHA + mean + residual + LayerNorm ----------------
// 1 wave per 16 rows (8 nodes). Rows interleave (node, comm[map[node]]).
__global__ __launch_bounds__(64) void mha_fused_kernel(
    const unsigned short* __restrict__ hbn, const unsigned short* __restrict__ hbc,
    const int* __restrict__ map,
    const unsigned short* __restrict__ WinB,   // [384][128] bf16
    const float* __restrict__ bin,             // [384]
    const unsigned short* __restrict__ WoutB,  // [128][128] bf16
    const float* __restrict__ bout,            // [128]
    const float* __restrict__ lng, const float* __restrict__ lnb,
    unsigned short* __restrict__ hfin, int nN, int nC) {
    __shared__ unsigned short qkv_s[16 * 384];
    __shared__ unsigned short obf_s[16 * 128];
    __shared__ float att_s[8 * 128];

    int b = blockIdx.x;
    int lane = threadIdx.x;
    int r = lane & 15, q = lane >> 4;

    // ---- phase A: in-proj GEMM (16 x 384) ----
    int anode = b * 8 + (r >> 1);
    if (anode >= nN) anode = nN - 1;
    const unsigned short* arow;
    if (r & 1) {
        int c = map[anode]; c = c < 0 ? 0 : (c >= nC ? nC - 1 : c);
        arow = hbc + (size_t)c * 128;
    } else {
        arow = hbn + (size_t)anode * 128;
    }
    bf16x8 afrag[4];
#pragma unroll
    for (int kc = 0; kc < 4; ++kc)
        afrag[kc] = *(const bf16x8*)(const void*)(arow + q * 8 + kc * 32);

    for (int n0 = 0; n0 < 384; n0 += 16) {
        const unsigned short* bp = WinB + (size_t)(n0 + r) * 128 + q * 8;
        f32x4 acc = {0.f, 0.f, 0.f, 0.f};
#pragma unroll
        for (int kc = 0; kc < 4; ++kc) {
            bf16x8 bfrag = *(const bf16x8*)(const void*)(bp + kc * 32);
            acc = __builtin_amdgcn_mfma_f32_16x16x32_bf16(afrag[kc], bfrag, acc, 0, 0, 0);
        }
        float bv = bin[n0 + r];
#pragma unroll
        for (int t = 0; t < 4; ++t)
            qkv_s[(q * 4 + t) * 384 + n0 + r] = f2b(acc[t] + bv);
    }
    __syncthreads();

    // ---- phase B: attention, lane = (node_local = lane>>3, head = lane&7) ----
    {
        int nl = lane >> 3, h = lane & 7;
        const unsigned short* r0 = qkv_s + (2 * nl) * 384;
        const unsigned short* r1 = r0 + 384;
        int ho = h * 16;
        float s00 = 0, s01 = 0, s10 = 0, s11 = 0;
#pragma unroll
        for (int d = 0; d < 16; ++d) {
            float q0 = b2f(r0[ho + d]),       q1 = b2f(r1[ho + d]);
            float k0 = b2f(r0[128 + ho + d]), k1 = b2f(r1[128 + ho + d]);
            s00 += q0 * k0; s01 += q0 * k1;
            s10 += q1 * k0; s11 += q1 * k1;
        }
        s00 *= 0.25f; s01 *= 0.25f; s10 *= 0.25f; s11 *= 0.25f;
        float m0 = fmaxf(s00, s01), m1 = fmaxf(s10, s11);
        float e00 = __expf(s00 - m0), e01 = __expf(s01 - m0);
        float e10 = __expf(s10 - m1), e11 = __expf(s11 - m1);
        float i0 = 1.f / (e00 + e01), i1 = 1.f / (e10 + e11);
        float a00 = e00 * i0, a01 = e01 * i0;
        float a10 = e10 * i1, a11 = e11 * i1;
        unsigned short* o0 = obf_s + (2 * nl) * 128 + ho;
        unsigned short* o1 = o0 + 128;
#pragma unroll
        for (int d = 0; d < 16; ++d) {
            float v0 = b2f(r0[256 + ho + d]), v1 = b2f(r1[256 + ho + d]);
            o0[d] = f2b(a00 * v0 + a01 * v1);
            o1[d] = f2b(a10 * v0 + a11 * v1);
        }
    }
    __syncthreads();

    // ---- phase C: out-proj GEMM (16 x 128) + bias + mean over S ----
    bf16x8 ofrag[4];
#pragma unroll
    for (int kc = 0; kc < 4; ++kc)
        ofrag[kc] = *(const bf16x8*)(const void*)(obf_s + r * 128 + q * 8 + kc * 32);

    for (int n0 = 0; n0 < 128; n0 += 16) {
        const unsigned short* bp = WoutB + (size_t)(n0 + r) * 128 + q * 8;
        f32x4 acc = {0.f, 0.f, 0.f, 0.f};
#pragma unroll
        for (int kc = 0; kc < 4; ++kc) {
            bf16x8 bfrag = *(const bf16x8*)(const void*)(bp + kc * 32);
            acc = __builtin_amdgcn_mfma_f32_16x16x32_bf16(ofrag[kc], bfrag, acc, 0, 0, 0);
        }
        float bv = bout[n0 + r];
        att_s[(q * 2 + 0) * 128 + n0 + r] = 0.5f * (acc[0] + acc[1]) + bv;
        att_s[(q * 2 + 1) * 128 + n0 + r] = 0.5f * (acc[2] + acc[3]) + bv;
    }
    __syncthreads();

    // ---- phase D: residual + LayerNorm (8 lanes per node, 16 cols each) ----
    {
        int nl = lane >> 3, j = lane & 7;
        int gnode = b * 8 + nl; if (gnode >= nN) gnode = nN - 1;
        const unsigned short* hrow = hbn + (size_t)gnode * 128 + j * 16;
        float x[16]; float s = 0.f, s2 = 0.f;
#pragma unroll
        for (int i = 0; i < 16; ++i) {
            x[i] = att_s[nl * 128 + j * 16 + i] + b2f(hrow[i]);
            s += x[i]; s2 += x[i] * x[i];
        }
        s += __shfl_xor(s, 1);  s2 += __shfl_xor(s2, 1);
        s += __shfl_xor(s, 2);  s2 += __shfl_xor(s2, 2);
        s += __shfl_xor(s, 4);  s2 += __shfl_xor(s2, 4);
        float mu = s * (1.f / 128.f);
        float var = s2 * (1.f / 128.f) - mu * mu;
        float rstd = rsqrtf(var + EPSV);
        unsigned short* orow = hfin + (size_t)gnode * 128 + j * 16;
#pragma unroll
        for (int i = 0; i < 16; ++i)
            orow[i] = f2b((x[i] - mu) * rstd * lng[j * 16 + i] + lnb[j * 16 + i]);
    }
}

// ---------------- classifier tail: BN+ReLU + Linear(64,10) + log_softmax ------
__global__ void final_kernel(const float* __restrict__ z, const float* __restrict__ bnp,
                             const float* __restrict__ W2,
                             const float* __restrict__ b2v,
                             float* __restrict__ out, int nN) {
    int node = blockIdx.x;
    int lane = threadIdx.x;  // 64
    float v = z[(size_t)node * 64 + lane] * bnp[lane] + bnp[64 + lane];
    v = fmaxf(v, 0.f);
    float p[10];
    const float* wrow = W2 + lane * 10;
#pragma unroll
    for (int c = 0; c < 10; ++c) p[c] = v * wrow[c];
#pragma unroll
    for (int off = 32; off >= 1; off >>= 1) {
#pragma unroll
        for (int c = 0; c < 10; ++c) p[c] += __shfl_xor(p[c], off);
    }
    float l[10], mx = -1e30f;
#pragma unroll
    for (int c = 0; c < 10; ++c) { l[c] = p[c] + b2v[c]; mx = fmaxf(mx, l[c]); }
    float se = 0.f;
#pragma unroll
    for (int c = 0; c < 10; ++c) se += expf(l[c] - mx);
    float lse = mx + logf(se);
    if (lane < 10) out[(size_t)node * 10 + lane] = l[lane] - lse;
}

// ---------------------------------------------------------------------------
static inline int cdiv(long a, long b) { return (int)((a + b - 1) / b); }

extern "C" void kernel_launch(void* const* d_in, const int* in_sizes, int n_in,
                              void* d_out, int out_size, void* d_ws, size_t ws_size,
                              hipStream_t stream) {
    const float* node_feat = (const float*)d_in[0];
    const int*   nedge     = (const int*)d_in[1];
    const float* comm_feat = (const float*)d_in[2];
    const int*   cedge     = (const int*)d_in[3];
    const int*   n2c       = (const int*)d_in[4];
    const float* node_W    = (const float*)d_in[5];
    const float* node_b    = (const float*)d_in[6];
    const float* node_g    = (const float*)d_in[7];
    const float* node_beta = (const float*)d_in[8];
    const float* comm_W    = (const float*)d_in[9];
    const float* comm_b    = (const float*)d_in[10];
    const float* comm_g    = (const float*)d_in[11];
    const float* comm_beta = (const float*)d_in[12];
    const float* attn_in_w = (const float*)d_in[13];
    const float* attn_in_b = (const float*)d_in[14];
    const float* attn_out_w= (const float*)d_in[15];
    const float* attn_out_b= (const float*)d_in[16];
    const float* ln_g      = (const float*)d_in[17];
    const float* ln_b      = (const float*)d_in[18];
    const float* cls_W1    = (const float*)d_in[19];
    const float* cls_b1    = (const float*)d_in[20];
    const float* cls_bn_g  = (const float*)d_in[21];
    const float* cls_bn_b  = (const float*)d_in[22];
    const float* cls_W2    = (const float*)d_in[23];
    const float* cls_b2    = (const float*)d_in[24];

    const int nN = in_sizes[0] / 128;
    const int nE = in_sizes[1] / 2;
    const int nC = in_sizes[2] / 128;
    const int cE = in_sizes[3] / 2;

    // ---- workspace layout ----
    char* ws = (char*)d_ws;
    size_t off = 0;
    auto alloc = [&](size_t bytes) -> char* {
        char* p = ws + off;
        off = (off + bytes + 255) & ~(size_t)255;
        return p;
    };
    // CSR (node)
    int*   cnt_n  = (int*)alloc((size_t)nN * 4);
    int*   rs_n   = (int*)alloc((size_t)(nN + 1) * 4);
    int*   cur_n  = (int*)alloc((size_t)nN * 4);
    int*   csrc_n = (int*)alloc((size_t)nE * 4);
    float* cw_n   = (float*)alloc((size_t)nE * 4);
    int*   bsum_n = (int*)alloc(256 * 4);
    float* dinv_n = (float*)alloc((size_t)nN * 4);
    // CSR (comm)
    int*   cnt_c  = (int*)alloc((size_t)nC * 4);
    int*   rs_c   = (int*)alloc((size_t)(nC + 1) * 4);
    int*   cur_c  = (int*)alloc((size_t)nC * 4);
    int*   csrc_c = (int*)alloc((size_t)cE * 4);
    float* cw_c   = (float*)alloc((size_t)cE * 4);
    int*   bsum_c = (int*)alloc(256 * 4);
    float* dinv_c = (float*)alloc((size_t)nC * 4);
    // activations
    unsigned short* hb_n  = (unsigned short*)alloc((size_t)nN * 256);
    unsigned short* hb_c  = (unsigned short*)alloc((size_t)nC * 256);
    unsigned short* cfb   = (unsigned short*)alloc((size_t)nC * 256);
    unsigned short* m_cb  = (unsigned short*)alloc((size_t)nC * 256);
    float*          agg_c = (float*)alloc((size_t)nC * 512);
    float*          bn_sums   = (float*)alloc(1024);
    float*          bn_params = (float*)alloc(1024);
    unsigned short* WtN  = (unsigned short*)alloc((size_t)3 * 16384 * 2);
    unsigned short* WtC  = (unsigned short*)alloc((size_t)3 * 16384 * 2);
    unsigned short* W1t  = (unsigned short*)alloc((size_t)64 * 128 * 2);
    unsigned short* WinB = (unsigned short*)alloc((size_t)384 * 128 * 2);
    unsigned short* WoutB= (unsigned short*)alloc((size_t)128 * 128 * 2);
    unsigned short* m_nb = (unsigned short*)alloc((size_t)nN * 256);   // bf16 messages
    float*          agg_n= (float*)alloc((size_t)nN * 512);            // f32 agg
    // aliases (disjoint liveness):
    unsigned short* nfb  = (unsigned short*)agg_n;  // node feat bf16; consumed by L0 gemm before gather writes agg_n
    unsigned short* hfin = m_nb;                    // written after node GCN done
    float*          z    = agg_n;                   // written after node GCN done

    // ---- CSR build (both graphs) ----
    hipMemsetAsync(cnt_n, 0, (size_t)nN * 4, stream);
    hipMemsetAsync(cur_n, 0, (size_t)nN * 4, stream);
    hipMemsetAsync(cnt_c, 0, (size_t)nC * 4, stream);
    hipMemsetAsync(cur_c, 0, (size_t)nC * 4, stream);
    count_kernel<<<cdiv(nE, 256), 256, 0, stream>>>(nedge + nE, cnt_n, nE);
    count_kernel<<<cdiv(cE, 256), 256, 0, stream>>>(cedge + cE, cnt_c, cE);
    dinv_kernel<<<cdiv(nN, 256), 256, 0, stream>>>(cnt_n, dinv_n, nN);
    dinv_kernel<<<cdiv(nC, 256), 256, 0, stream>>>(cnt_c, dinv_c, nC);
    int nbN = cdiv(nN, 1024), nbC = cdiv(nC, 1024);
    scan_block_kernel<<<nbN, 1024, 0, stream>>>(cnt_n, rs_n, bsum_n, nN);
    scan_block_kernel<<<nbC, 1024, 0, stream>>>(cnt_c, rs_c, bsum_c, nC);
    scan_sums_kernel<<<1, 64, 0, stream>>>(bsum_n, nbN);
    scan_sums_kernel<<<1, 64, 0, stream>>>(bsum_c, nbC);
    scan_add_kernel<<<cdiv(nN + 1, 256), 256, 0, stream>>>(rs_n, bsum_n, nN, nE);
    scan_add_kernel<<<cdiv(nC + 1, 256), 256, 0, stream>>>(rs_c, bsum_c, nC, cE);
    fill_kernel<<<cdiv(nE, 256), 256, 0, stream>>>(nedge, nedge + nE, dinv_n, rs_n, cur_n, csrc_n, cw_n, nE);
    fill_kernel<<<cdiv(cE, 256), 256, 0, stream>>>(cedge, cedge + cE, dinv_c, rs_c, cur_c, csrc_c, cw_c, cE);

    // ---- weight transposes/casts ----
    for (int i = 0; i < 3; ++i) {
        transpose_kernel<<<64, 256, 0, stream>>>(node_W + i * 16384, WtN + i * 16384, 128, 128);
        transpose_kernel<<<64, 256, 0, stream>>>(comm_W + i * 16384, WtC + i * 16384, 128, 128);
    }
    transpose_kernel<<<32, 256, 0, stream>>>(cls_W1, W1t, 128, 64);
    cast_kernel<<<192, 256, 0, stream>>>(attn_in_w, WinB, 49152);
    cast_kernel<<<64, 256, 0, stream>>>(attn_out_w, WoutB, 16384);
    cast_kernel<<<cdiv((long)nC * 128, 256), 256, 0, stream>>>(comm_feat, cfb, nC * 128);

    // ---- GCN stacks ----
    auto gcn_layer = [&](int layer, int n, const int* rs, const int* csrc, const float* cw,
                         const float* dinv, const unsigned short* A, const unsigned short* Wt,
                         const float* bvec, const float* g, const float* beta,
                         unsigned short* m, float* agg, unsigned short* hb) {
        int waves = (n + 15) / 16;
        gemm_kernel<true><<<cdiv((long)waves * 64, 256), 256, 0, stream>>>(
            A, Wt, (const float*)nullptr, m, n, 128);
        gather_kernel<<<cdiv((long)n * 64, 256), 256, 0, stream>>>(
            m, rs, csrc, cw, dinv, bvec, agg, n);
        hipMemsetAsync(bn_sums, 0, 1024, stream);
        bn_stats_kernel<<<cdiv(n, 128), 128, 0, stream>>>(agg, bn_sums, n, 128, 128);
        bn_finalize_kernel<<<1, 128, 0, stream>>>(bn_sums, g, beta, bn_params, n, 128);
        bn_apply_kernel<<<cdiv((long)n * 128, 256), 256, 0, stream>>>(
            agg, bn_params, hb, n * 128, layer > 0 ? 1 : 0);
    };

    cast_kernel<<<cdiv((long)nN * 128, 256), 256, 0, stream>>>(node_feat, nfb, nN * 128);
    for (int i = 0; i < 3; ++i)
        gcn_layer(i, nN, rs_n, csrc_n, cw_n, dinv_n, i == 0 ? nfb : hb_n, WtN + i * 16384,
                  node_b + i * 128, node_g + i * 128, node_beta + i * 128,
                  m_nb, agg_n, hb_n);
    for (int i = 0; i < 3; ++i)
        gcn_layer(i, nC, rs_c, csrc_c, cw_c, dinv_c, i == 0 ? cfb : hb_c, WtC + i * 16384,
                  comm_b + i * 128, comm_g + i * 128, comm_beta + i * 128,
                  m_cb, agg_c, hb_c);

    // ---- fused MHA + mean + residual + LN -> hfin (aliases m_nb) ----
    mha_fused_kernel<<<cdiv(nN, 8), 64, 0, stream>>>(
        hb_n, hb_c, n2c, WinB, attn_in_b, WoutB, attn_out_b, ln_g, ln_b, hfin, nN, nC);

    // ---- classifier ----
    int waves1 = (nN + 15) / 16;
    gemm_kernel<false><<<cdiv((long)waves1 * 64, 256), 256, 0, stream>>>(
        hfin, W1t, cls_b1, z, nN, 64);
    hipMemsetAsync(bn_sums, 0, 1024, stream);
    bn_stats_kernel<<<cdiv(nN, 128), 64, 0, stream>>>(z, bn_sums, nN, 64, 128);
    bn_finalize_kernel<<<1, 64, 0, stream>>>(bn_sums, cls_bn_g, cls_bn_b, bn_params, nN, 64);
    final_kernel<<<nN, 64, 0, stream>>>(z, bn_params, cls_W2, cls_b2,
                                        (float*)d_out, nN);
}